// Round 3
// baseline (431.141 us; speedup 1.0000x reference)
//
#include <hip/hip_runtime.h>

// RGCN embedding, MI355X.  R12: gemm1/gemm2 latency-chain fixes.  R11 counters
// (gemm1 78.6us: WRITE=200MB exact, hbm 2.79 TB/s = 44% achievable, Mfma 12.5%,
// VALU 17.7%, Occ 31%) -> not write-roofline, latency-bound serial epilogue +
// low residency.  Changes: (1) m-groups 1024->512 rows, 2x blocks (gemm1 3200,
// gemm2 1600); (2) f2b bit-trick -> v_cvt_pk_bf16_f32 (2 elems/instr, same RNE);
// (3) drop trailing lgkmcnt(0) (same-wave DS in-order; compiler auto-waits
// ds_read data before dependent store).  Rest unchanged from R11.
#define N_NODES 100000
#define N_PAD   100096
#define E_EDGES 3200000
#define NB      392            // buckets of 256 nodes
#define BCAP    12288
#define EPB     8192           // edges per kbinA block (32/thread)

typedef float f32x4 __attribute__((ext_vector_type(4)));
typedef __bf16 bf16x8 __attribute__((ext_vector_type(8)));

__device__ __forceinline__ float b2f(unsigned int u) {
    union { unsigned int i; float f; } x; x.i = u << 16; return x.f;
}
__device__ __forceinline__ unsigned short f2b(float f) {
    union { float f; unsigned int i; } x; x.f = f;
    unsigned int u = x.i + 0x7FFFu + ((x.i >> 16) & 1u);
    return (unsigned short)(u >> 16);
}
// pack 2 f32 -> 2 bf16 (RNE), lo in bits[15:0]
__device__ __forceinline__ unsigned int cvt2(float lo, float hi) {
    unsigned int r;
    asm("v_cvt_pk_bf16_f32 %0, %1, %2" : "=v"(r) : "v"(lo), "v"(hi));
    return r;
}

__global__ __launch_bounds__(256) void kcur(int* __restrict__ gCursor) {
    int id = blockIdx.x * 256 + threadIdx.x;
    if (id < NB) gCursor[id] = id * BCAP;
}

// emb f32 -> bf16, padded to N_PAD rows (pad = 0)
__global__ __launch_bounds__(256) void kemb(const float* __restrict__ emb,
                                            unsigned short* __restrict__ embb) {
    int id = blockIdx.x * 256 + threadIdx.x;
    if (id >= N_PAD * 128 / 8) return;
    size_t base = (size_t)id * 8;
    ushort4 o0 = {0, 0, 0, 0}, o1 = {0, 0, 0, 0};
    if (base < (size_t)N_NODES * 128) {
        float4 v0 = *(const float4*)(emb + base);
        float4 v1 = *(const float4*)(emb + base + 4);
        o0.x = f2b(v0.x); o0.y = f2b(v0.y); o0.z = f2b(v0.z); o0.w = f2b(v0.w);
        o1.x = f2b(v1.x); o1.y = f2b(v1.y); o1.z = f2b(v1.z); o1.w = f2b(v1.w);
    }
    *(ushort4*)(embb + base) = o0;
    *(ushort4*)(embb + base + 4) = o1;
}

// w1T[j][k] = sum_b comps1[r,b]*bases1[b,k,h], j=r*32+h  (bf16, [1024][128])
__global__ __launch_bounds__(256) void kw1(const float* __restrict__ comps1,
                                           const float* __restrict__ bases1,
                                           unsigned short* __restrict__ w1T) {
    int id = blockIdx.x * 256 + threadIdx.x;
    if (id >= 1024 * 128) return;
    int k = id & 127, j = id >> 7;
    int r = j >> 5, h = j & 31;
    float s = 0.f;
#pragma unroll
    for (int b = 0; b < 16; b++)
        s += comps1[r * 16 + b] * bases1[b * 4096 + k * 32 + h];
    w1T[(size_t)j * 128 + k] = f2b(s);
}

// w2T[j2][h] = sum_b comps2[r,b]*bases2[b,h,c], j2=r*16+c  (bf16, [512][32])
__global__ __launch_bounds__(256) void kw2(const float* __restrict__ comps2,
                                           const float* __restrict__ bases2,
                                           unsigned short* __restrict__ w2T) {
    int id = blockIdx.x * 256 + threadIdx.x;
    if (id >= 512 * 32) return;
    int h = id & 31, j = id >> 5;
    int r = j >> 4, c = j & 15;
    float s = 0.f;
#pragma unroll
    for (int b = 0; b < 16; b++)
        s += comps2[r * 16 + b] * bases2[b * 512 + h * 16 + c];
    w2T[(size_t)j * 32 + h] = f2b(s);
}

// Single-pass in-block counting sort by bucket (fr>>8).
// word=(frlo<<22)|(rel<<17)|to.  Per-bucket runs flushed contiguously.
__global__ __launch_bounds__(256) void kbinA(const int* __restrict__ rel,
                                             const int* __restrict__ fr,
                                             const int* __restrict__ to,
                                             int* __restrict__ gCursor,
                                             unsigned int* __restrict__ stage) {
    __shared__ int cnt[NB];
    __shared__ int lexcl[NB + 1];
    __shared__ int sdelta[NB];
    __shared__ int sa[512], sb_[512];
    __shared__ unsigned int sortbuf[EPB];
    int tid = threadIdx.x;
    int g40 = blockIdx.x * (EPB / 4);          // int4-group base
    unsigned int w_[32];
    int bk[32];
    for (int i = tid; i < NB; i += 256) cnt[i] = 0;
    __syncthreads();
    // load 32 edges into registers, LDS histogram
#pragma unroll
    for (int i = 0; i < 8; i++) {
        int g4 = g40 + i * 256 + tid;
        if (g4 < E_EDGES / 4) {
            int4 f4 = ((const int4*)fr)[g4];
            int4 r4 = ((const int4*)rel)[g4];
            int4 t4 = ((const int4*)to)[g4];
            int fa[4] = {f4.x, f4.y, f4.z, f4.w};
            int ra[4] = {r4.x, r4.y, r4.z, r4.w};
            int ta[4] = {t4.x, t4.y, t4.z, t4.w};
#pragma unroll
            for (int u = 0; u < 4; u++) {
                int b = fa[u] >> 8;
                w_[i * 4 + u] = ((unsigned int)(fa[u] & 255) << 22) |
                                ((unsigned int)ra[u] << 17) | (unsigned int)ta[u];
                bk[i * 4 + u] = b;
                atomicAdd(&cnt[b], 1);
            }
        } else {
#pragma unroll
            for (int u = 0; u < 4; u++) bk[i * 4 + u] = -1;
        }
    }
    __syncthreads();
    // inclusive scan of cnt[0..NB) over padded 512 domain (256 thr x 2 elem)
    sa[tid] = (tid < NB) ? cnt[tid] : 0;
    sa[tid + 256] = (tid + 256 < NB) ? cnt[tid + 256] : 0;
    __syncthreads();
    int* src = sa; int* dst = sb_;
    for (int ofs = 1; ofs < 512; ofs <<= 1) {
        int x0 = src[tid];
        if (tid >= ofs) x0 += src[tid - ofs];
        int x1 = src[tid + 256] + src[tid + 256 - ofs];
        __syncthreads();
        dst[tid] = x0; dst[tid + 256] = x1;
        __syncthreads();
        int* tmp = src; src = dst; dst = tmp;
    }
    // reserve global ranges, build local offsets
    for (int b = tid; b < NB; b += 256) {
        int c = cnt[b];
        int lex = src[b] - c;
        lexcl[b] = lex;
        int gb = 0;
        if (c) gb = atomicAdd(&gCursor[b], c);
        sdelta[b] = gb - lex;
        cnt[b] = 0;                       // reuse as rank counter
    }
    if (tid == 0) lexcl[NB] = src[NB - 1];
    __syncthreads();
    // rank-scatter into LDS sorted buffer
#pragma unroll
    for (int i = 0; i < 32; i++) {
        if (bk[i] >= 0) {
            int rank = atomicAdd(&cnt[bk[i]], 1);
            sortbuf[lexcl[bk[i]] + rank] = w_[i];
        }
    }
    __syncthreads();
    // flush per-bucket contiguous runs
    int wv = tid >> 6, lane = tid & 63;
    for (int b = wv; b < NB; b += 4) {
        int s = lexcl[b], e = lexcl[b + 1];
        int d = sdelta[b];
        for (int i = s + lane; i < e; i += 64)
            stage[d + i] = sortbuf[i];
    }
}

// exclusive scan of bucket counts -> bucketBase
__global__ __launch_bounds__(512) void kscan(const int* __restrict__ gCursor,
                                             int* __restrict__ bucketBase) {
    __shared__ int a[512], b[512];
    int t = threadIdx.x;
    int v = (t < NB) ? (gCursor[t] - t * BCAP) : 0;
    a[t] = v;
    __syncthreads();
    int* src = a; int* dst = b;
    for (int ofs = 1; ofs < 512; ofs <<= 1) {
        int x = src[t];
        if (t >= ofs) x += src[t - ofs];
        __syncthreads();
        dst[t] = x;
        __syncthreads();
        int* tmp = src; src = dst; dst = tmp;
    }
    if (t < NB) bucketBase[t] = src[t] - v;
}

// Per-bucket: LDS node-hist -> scan -> rowptr; (node,rel)-hist -> deg;
// scatter packed = (deg<<22)|(rel<<17)|to.  uint4 stage loads.
__global__ __launch_bounds__(256) void kscatter2(const unsigned int* __restrict__ stage,
                                                 const int* __restrict__ gCursor,
                                                 const int* __restrict__ bucketBase,
                                                 int* __restrict__ rowptr,
                                                 unsigned int* __restrict__ packed) {
    __shared__ int hist[256], hexcl[256], rk[256], sa[256], sb[256];
    __shared__ int hist2[256 * 32];
    int b = blockIdx.x, t = threadIdx.x;
    int nb = gCursor[b] - b * BCAP;
    int sbase = b * BCAP;
    int gbase = bucketBase[b];
    int nb4 = nb >> 2;
    hist[t] = 0; rk[t] = 0;
    for (int i = t; i < 256 * 32; i += 256) hist2[i] = 0;
    __syncthreads();
    for (int i4 = t; i4 < nb4; i4 += 256) {
        uint4 p4 = ((const uint4*)(stage + sbase))[i4];
        unsigned int pa[4] = {p4.x, p4.y, p4.z, p4.w};
#pragma unroll
        for (int u = 0; u < 4; u++) {
            atomicAdd(&hist[pa[u] >> 22], 1);
            atomicAdd(&hist2[((pa[u] >> 22) << 5) | ((pa[u] >> 17) & 31)], 1);
        }
    }
    for (int i = (nb4 << 2) + t; i < nb; i += 256) {
        unsigned int pk = stage[sbase + i];
        atomicAdd(&hist[pk >> 22], 1);
        atomicAdd(&hist2[((pk >> 22) << 5) | ((pk >> 17) & 31)], 1);
    }
    __syncthreads();
    int v = hist[t];
    sa[t] = v;
    __syncthreads();
    int* src = sa; int* dst = sb;
    for (int ofs = 1; ofs < 256; ofs <<= 1) {
        int x = src[t];
        if (t >= ofs) x += src[t - ofs];
        __syncthreads();
        dst[t] = x;
        __syncthreads();
        int* tmp = src; src = dst; dst = tmp;
    }
    int excl = src[t] - v;
    hexcl[t] = excl;
    rowptr[b * 256 + t] = gbase + excl;
    __syncthreads();
    for (int i4 = t; i4 < nb4; i4 += 256) {
        uint4 p4 = ((const uint4*)(stage + sbase))[i4];
        unsigned int pa[4] = {p4.x, p4.y, p4.z, p4.w};
#pragma unroll
        for (int u = 0; u < 4; u++) {
            int frlo = pa[u] >> 22;
            int rank = atomicAdd(&rk[frlo], 1);
            int dg = min(hist2[(frlo << 5) | ((pa[u] >> 17) & 31)], 1023);
            packed[gbase + hexcl[frlo] + rank] = ((unsigned int)dg << 22) | (pa[u] & 0x3FFFFFu);
        }
    }
    for (int i = (nb4 << 2) + t; i < nb; i += 256) {
        unsigned int pk = stage[sbase + i];
        int frlo = pk >> 22;
        int rank = atomicAdd(&rk[frlo], 1);
        int dg = min(hist2[(frlo << 5) | ((pk >> 17) & 31)], 1023);
        packed[gbase + hexcl[frlo] + rank] = ((unsigned int)dg << 22) | (pk & 0x3FFFFFu);
    }
}

// GEMM1 (streaming-wave + LDS-pack epilogue): xw[m][j] = sum_k embb[m][k]*w1T[j][k].
// Wave: B-slab 64n x 128k resident; 8 m-iters of 16 rows (512-row groups),
// ping-pong A prefetch.  Epilogue: cvt_pk acc -> wave-private LDS (136-short
// row stride) -> uint4 reads -> 2 stores/iter, each 8 full 128B lines.
__global__ __launch_bounds__(256) void gemm1(const unsigned short* __restrict__ embb,
                                             const unsigned short* __restrict__ w1T,
                                             unsigned short* __restrict__ xw) {
    __shared__ unsigned short ldsT[4 * 16 * 136];
    int id = blockIdx.x;
    int xcd = id & 7, w = id >> 3;
    int bn = w & 15, mgl = w >> 4;
    int mg = mgl * 8 + xcd;
    if (mg >= 196) return;
    int lane = threadIdx.x & 63, wave = threadIdx.x >> 6;
    int m_ = lane & 15, q = lane >> 4;
    unsigned short* tw = &ldsT[wave * 16 * 136];
    bf16x8 B[4][4];
    const unsigned short* Bbase = w1T + (size_t)(bn * 64 + m_) * 128 + q * 8;
#pragma unroll
    for (int j = 0; j < 4; j++)
#pragma unroll
        for (int k0 = 0; k0 < 4; k0++)
            B[j][k0] = *(const bf16x8*)(Bbase + j * 16 * 128 + k0 * 32);
    int mrow0 = mg * 512 + wave * 16;
    const unsigned short* Abase = embb + (size_t)(mrow0 + m_) * 128 + q * 8;
    bf16x8 a0[4], a1[4];
    if (mrow0 < N_PAD) {
#pragma unroll
        for (int k0 = 0; k0 < 4; k0++)
            a0[k0] = *(const bf16x8*)(Abase + k0 * 32);
    }
#pragma unroll
    for (int t = 0; t < 8; t++) {
        int m0 = mrow0 + t * 64;
        if (m0 >= N_PAD) break;
        bf16x8* acur = (t & 1) ? a1 : a0;
        bf16x8* anext = (t & 1) ? a0 : a1;
        if (t < 7 && m0 + 64 < N_PAD) {
#pragma unroll
            for (int k0 = 0; k0 < 4; k0++)
                anext[k0] = *(const bf16x8*)(Abase + (size_t)(t + 1) * 64 * 128 + k0 * 32);
        }
        f32x4 acc[4] = {};
#pragma unroll
        for (int k0 = 0; k0 < 4; k0++)
#pragma unroll
            for (int j = 0; j < 4; j++)
                acc[j] = __builtin_amdgcn_mfma_f32_16x16x32_bf16(B[j][k0], acur[k0], acc[j], 0, 0, 0);
        // pack tile (rows m_, cols jj*16+q*4) into LDS via cvt_pk
#pragma unroll
        for (int jj = 0; jj < 4; jj++) {
            uint2 s;
            s.x = cvt2(acc[jj][0], acc[jj][1]);
            s.y = cvt2(acc[jj][2], acc[jj][3]);
            *(uint2*)(tw + m_ * 136 + jj * 16 + q * 4) = s;
        }
        __asm__ volatile("s_waitcnt lgkmcnt(0)" ::: "memory");
#pragma unroll
        for (int ri = 0; ri < 2; ri++) {
            int row = (lane >> 3) + ri * 8;
            int c = lane & 7;
            uint4 v = *(const uint4*)(tw + row * 136 + c * 8);
            int grow = m0 + row;
            if (grow < N_NODES)
                *(uint4*)(xw + (size_t)grow * 1024 + bn * 64 + c * 8) = v;
        }
    }
}

// edge1csr: one wave per node, single pass (deg packed).  8 edges/instr.
__global__ __launch_bounds__(256) void edge1csr(const unsigned int* __restrict__ packed,
                                                const int* __restrict__ rowptr,
                                                const unsigned short* __restrict__ xw,
                                                const float* __restrict__ bias1,
                                                unsigned short* __restrict__ h1b) {
    __shared__ unsigned int ebuf[4 * 64];
    __shared__ float vbuf[4 * 64];
    int wave = threadIdx.x >> 6, lane = threadIdx.x & 63;
    int f = blockIdx.x * 4 + wave;
    if (f >= N_NODES) return;
    int s = rowptr[f], k = rowptr[f + 1] - s;
    int sub = lane & 7, p = lane >> 3;
    f32x4 acc = {0.f, 0.f, 0.f, 0.f};
    for (int base = 0; base < k; base += 64) {
        int e = base + lane;
        if (e < k) {
            unsigned int pk = packed[s + e];
            ebuf[wave * 64 + lane] = pk;
            vbuf[wave * 64 + lane] = 1.0f / (float)(pk >> 22);
        }
        int cnum = min(64, k - base);
        int nst = (cnum + 7) >> 3;
#pragma unroll 4
        for (int i = 0; i < nst; i++) {
            int ei = (i << 3) + p;
            if (ei < cnum) {
                unsigned int pk = ebuf[wave * 64 + ei];
                float v = vbuf[wave * 64 + ei];
                int t_ = pk & 0x1FFFF, r = (pk >> 17) & 31;
                ushort4 raw = *(const ushort4*)(xw + (size_t)t_ * 1024 + (r << 5) + (sub << 2));
                acc.x += v * b2f(raw.x); acc.y += v * b2f(raw.y);
                acc.z += v * b2f(raw.z); acc.w += v * b2f(raw.w);
            }
        }
    }
#pragma unroll
    for (int ofs = 8; ofs < 64; ofs <<= 1) {
        acc.x += __shfl_xor(acc.x, ofs, 64);
        acc.y += __shfl_xor(acc.y, ofs, 64);
        acc.z += __shfl_xor(acc.z, ofs, 64);
        acc.w += __shfl_xor(acc.w, ofs, 64);
    }
    if (p == 0) {
        int h = sub << 2;
        ushort4 o;
        o.x = f2b(fmaxf(acc.x + bias1[h + 0], 0.f));
        o.y = f2b(fmaxf(acc.y + bias1[h + 1], 0.f));
        o.z = f2b(fmaxf(acc.z + bias1[h + 2], 0.f));
        o.w = f2b(fmaxf(acc.w + bias1[h + 3], 0.f));
        *(ushort4*)(h1b + (size_t)f * 32 + h) = o;
    }
}

// GEMM2 (streaming-wave + LDS-pack epilogue): z[m][j2] = sum_h h1b[m][h]*w2T[j2][h].
__global__ __launch_bounds__(256) void gemm2(const unsigned short* __restrict__ h1b,
                                             const unsigned short* __restrict__ w2T,
                                             unsigned short* __restrict__ z) {
    __shared__ unsigned short ldsT[4 * 16 * 136];
    int id = blockIdx.x;
    int xcd = id & 7, w = id >> 3;
    int bn = w & 7, mgl = w >> 3;
    int mg = mgl * 8 + xcd;
    if (mg >= 196) return;
    int lane = threadIdx.x & 63, wave = threadIdx.x >> 6;
    int m_ = lane & 15, q = lane >> 4;
    unsigned short* tw = &ldsT[wave * 16 * 136];
    bf16x8 B[4];
    const unsigned short* Bbase = w2T + (size_t)(bn * 64 + m_) * 32 + q * 8;
#pragma unroll
    for (int j = 0; j < 4; j++)
        B[j] = *(const bf16x8*)(Bbase + j * 16 * 32);
    int mrow0 = mg * 512 + wave * 32;
    const unsigned short* Abase = h1b + (size_t)(mrow0 + m_) * 32 + q * 8;
    bf16x8 a0[2], a1[2];
    if (mrow0 < N_PAD) {
        a0[0] = *(const bf16x8*)(Abase);
        a0[1] = *(const bf16x8*)(Abase + 16 * 32);
    }
#pragma unroll
    for (int t = 0; t < 4; t++) {
        int m0 = mrow0 + t * 128;
        if (m0 >= N_PAD) break;
        bf16x8* acur = (t & 1) ? a1 : a0;
        bf16x8* anext = (t & 1) ? a0 : a1;
        if (t < 3 && m0 + 128 < N_PAD) {
            anext[0] = *(const bf16x8*)(Abase + (size_t)(t + 1) * 128 * 32);
            anext[1] = *(const bf16x8*)(Abase + (size_t)(t + 1) * 128 * 32 + 16 * 32);
        }
        f32x4 acc[2][4] = {};
#pragma unroll
        for (int i = 0; i < 2; i++)
#pragma unroll
            for (int j = 0; j < 4; j++)
                acc[i][j] = __builtin_amdgcn_mfma_f32_16x16x32_bf16(B[j], acur[i], acc[i][j], 0, 0, 0);
#pragma unroll
        for (int i = 0; i < 2; i++) {
#pragma unroll
            for (int jj = 0; jj < 4; jj++) {
                uint2 s;
                s.x = cvt2(acc[i][jj][0], acc[i][jj][1]);
                s.y = cvt2(acc[i][jj][2], acc[i][jj][3]);
                *(uint2*)(tw + m_ * 136 + jj * 16 + q * 4) = s;
            }
            __asm__ volatile("s_waitcnt lgkmcnt(0)" ::: "memory");
#pragma unroll
            for (int ri = 0; ri < 2; ri++) {
                int row = (lane >> 3) + ri * 8;
                int c = lane & 7;
                uint4 v = *(const uint4*)(tw + row * 136 + c * 8);
                int grow = m0 + i * 16 + row;
                if (grow < N_NODES)
                    *(uint4*)(z + (size_t)grow * 512 + bn * 64 + c * 8) = v;
            }
            __asm__ volatile("s_waitcnt lgkmcnt(0)" ::: "memory");
        }
    }
}

// edge2csr: one wave per node, single pass.  16 edges/instr, float4 store.
__global__ __launch_bounds__(256) void edge2csr(const unsigned int* __restrict__ packed,
                                                const int* __restrict__ rowptr,
                                                const unsigned short* __restrict__ z,
                                                const float* __restrict__ bias2,
                                                float* __restrict__ out) {
    __shared__ unsigned int ebuf[4 * 64];
    __shared__ float vbuf[4 * 64];
    int wave = threadIdx.x >> 6, lane = threadIdx.x & 63;
    int f = blockIdx.x * 4 + wave;
    if (f >= N_NODES) return;
    int s = rowptr[f], k = rowptr[f + 1] - s;
    int sub = lane & 3, p = lane >> 2;
    f32x4 acc = {0.f, 0.f, 0.f, 0.f};
    for (int base = 0; base < k; base += 64) {
        int e = base + lane;
        if (e < k) {
            unsigned int pk = packed[s + e];
            ebuf[wave * 64 + lane] = pk;
            vbuf[wave * 64 + lane] = 1.0f / (float)(pk >> 22);
        }
        int cnum = min(64, k - base);
        int nst = (cnum + 15) >> 4;
#pragma unroll 4
        for (int i = 0; i < nst; i++) {
            int ei = (i << 4) + p;
            if (ei < cnum) {
                unsigned int pk = ebuf[wave * 64 + ei];
                float v = vbuf[wave * 64 + ei];
                int t_ = pk & 0x1FFFF, r = (pk >> 17) & 31;
                ushort4 raw = *(const ushort4*)(z + (size_t)t_ * 512 + (r << 4) + (sub << 2));
                acc.x += v * b2f(raw.x); acc.y += v * b2f(raw.y);
                acc.z += v * b2f(raw.z); acc.w += v * b2f(raw.w);
            }
        }
    }
#pragma unroll
    for (int ofs = 4; ofs < 64; ofs <<= 1) {
        acc.x += __shfl_xor(acc.x, ofs, 64);
        acc.y += __shfl_xor(acc.y, ofs, 64);
        acc.z += __shfl_xor(acc.z, ofs, 64);
        acc.w += __shfl_xor(acc.w, ofs, 64);
    }
    if (p == 0) {
        int c = sub << 2;
        float4 o;
        o.x = acc.x + bias2[c + 0];
        o.y = acc.y + bias2[c + 1];
        o.z = acc.z + bias2[c + 2];
        o.w = acc.w + bias2[c + 3];
        *(float4*)(out + (size_t)f * 16 + c) = o;
    }
}

extern "C" void kernel_launch(void* const* d_in, const int* in_sizes, int n_in,
                              void* d_out, int out_size, void* d_ws, size_t ws_size,
                              hipStream_t stream) {
    (void)in_sizes; (void)n_in; (void)out_size; (void)ws_size;
    const float* emb    = (const float*)d_in[0];
    const float* comps1 = (const float*)d_in[1];
    const float* bases1 = (const float*)d_in[2];
    const float* comps2 = (const float*)d_in[3];
    const float* bases2 = (const float*)d_in[4];
    const float* bias1  = (const float*)d_in[5];
    const float* bias2  = (const float*)d_in[6];
    const int* rel = (const int*)d_in[7];
    const int* fr  = (const int*)d_in[8];
    const int* to  = (const int*)d_in[9];
    float* out = (float*)d_out;
    char* ws = (char*)d_ws;

    // workspace layout (bytes); total ~250.3 MB
    int* gCursor         = (int*)(ws);                        // 1,568
    int* bucketBase      = (int*)(ws + 2048);                 // 1,568
    int* rowptr          = (int*)(ws + 4096);                 // 401,412
    unsigned int* packed = (unsigned int*)(ws + 406528);      // 12,800,000
    unsigned short* h1b  = (unsigned short*)(ws + 13206528);  // 6,406,144 (N_PAD x 32)
    unsigned short* w1T  = (unsigned short*)(ws + 19612672);  // 262,144
    unsigned short* w2T  = (unsigned short*)(ws + 19874816);  // 32,768
    unsigned short* embb = (unsigned short*)(ws + 19907584);  // 25,624,576 (N_PAD x 128)
    unsigned short* xw   = (unsigned short*)(ws + 45532160);  // 204,800,000
    unsigned short* z    = xw;                 // alias: xw dead before gemm2
    unsigned int* stage  = (unsigned int*)xw;  // alias: stage dead before gemm1

    kcur<<<2, 256, 0, stream>>>(gCursor);
    kemb<<<6256, 256, 0, stream>>>(emb, embb);
    kw1<<<512, 256, 0, stream>>>(comps1, bases1, w1T);
    kw2<<<64, 256, 0, stream>>>(comps2, bases2, w2T);
    kbinA<<<(E_EDGES + EPB - 1) / EPB, 256, 0, stream>>>(rel, fr, to, gCursor, stage);
    kscan<<<1, 512, 0, stream>>>(gCursor, bucketBase);
    kscatter2<<<NB, 256, 0, stream>>>(stage, gCursor, bucketBase, rowptr, packed);
    gemm1<<<3200, 256, 0, stream>>>(embb, w1T, xw);    // 8 xcd * 16 bn * 25 mgl
    edge1csr<<<25000, 256, 0, stream>>>(packed, rowptr, xw, bias1, h1b);
    gemm2<<<1600, 256, 0, stream>>>(h1b, w2T, z);      // 8 xcd * 8 bn * 25 mgl
    edge2csr<<<25000, 256, 0, stream>>>(packed, rowptr, z, bias2, out);
}

// Round 4
// 423.785 us; speedup vs baseline: 1.0174x; 1.0174x over previous
//
#include <hip/hip_runtime.h>

// RGCN embedding, MI355X.  R13: gemm1 write-stream contiguity.  R12 post-mortem:
// 2x blocks HURT (78.6->85.3us; hbm 2.79->2.58 TB/s; WRITE pinned 200MB) ->
// gemm1 is write-throughput-bound and throughput degrades with MORE concurrent
// narrow streams (DRAM page thrash).  New gemm1: 4 waves/block share the same
// 16 output rows, own adjacent 64-col blocks; pack into one shared LDS tile
// (16 x 256, stride 260) and store 512B-contiguous per row (4x R11's 128B).
// Consecutive blocks = complementary bn4 of same rows -> same DRAM pages.
// Grid 1568, 16 iters, 2 barriers/iter.  gemm2 reverted to R11 verbatim.
#define N_NODES 100000
#define N_PAD   100096
#define E_EDGES 3200000
#define NB      392            // buckets of 256 nodes
#define BCAP    12288
#define EPB     8192           // edges per kbinA block (32/thread)

typedef float f32x4 __attribute__((ext_vector_type(4)));
typedef __bf16 bf16x8 __attribute__((ext_vector_type(8)));

__device__ __forceinline__ float b2f(unsigned int u) {
    union { unsigned int i; float f; } x; x.i = u << 16; return x.f;
}
__device__ __forceinline__ unsigned short f2b(float f) {
    union { float f; unsigned int i; } x; x.f = f;
    unsigned int u = x.i + 0x7FFFu + ((x.i >> 16) & 1u);
    return (unsigned short)(u >> 16);
}
// pack 2 f32 -> 2 bf16 (RNE), lo in bits[15:0]
__device__ __forceinline__ unsigned int cvt2(float lo, float hi) {
    unsigned int r;
    asm("v_cvt_pk_bf16_f32 %0, %1, %2" : "=v"(r) : "v"(lo), "v"(hi));
    return r;
}

__global__ __launch_bounds__(256) void kcur(int* __restrict__ gCursor) {
    int id = blockIdx.x * 256 + threadIdx.x;
    if (id < NB) gCursor[id] = id * BCAP;
}

// emb f32 -> bf16, padded to N_PAD rows (pad = 0)
__global__ __launch_bounds__(256) void kemb(const float* __restrict__ emb,
                                            unsigned short* __restrict__ embb) {
    int id = blockIdx.x * 256 + threadIdx.x;
    if (id >= N_PAD * 128 / 8) return;
    size_t base = (size_t)id * 8;
    ushort4 o0 = {0, 0, 0, 0}, o1 = {0, 0, 0, 0};
    if (base < (size_t)N_NODES * 128) {
        float4 v0 = *(const float4*)(emb + base);
        float4 v1 = *(const float4*)(emb + base + 4);
        o0.x = f2b(v0.x); o0.y = f2b(v0.y); o0.z = f2b(v0.z); o0.w = f2b(v0.w);
        o1.x = f2b(v1.x); o1.y = f2b(v1.y); o1.z = f2b(v1.z); o1.w = f2b(v1.w);
    }
    *(ushort4*)(embb + base) = o0;
    *(ushort4*)(embb + base + 4) = o1;
}

// w1T[j][k] = sum_b comps1[r,b]*bases1[b,k,h], j=r*32+h  (bf16, [1024][128])
__global__ __launch_bounds__(256) void kw1(const float* __restrict__ comps1,
                                           const float* __restrict__ bases1,
                                           unsigned short* __restrict__ w1T) {
    int id = blockIdx.x * 256 + threadIdx.x;
    if (id >= 1024 * 128) return;
    int k = id & 127, j = id >> 7;
    int r = j >> 5, h = j & 31;
    float s = 0.f;
#pragma unroll
    for (int b = 0; b < 16; b++)
        s += comps1[r * 16 + b] * bases1[b * 4096 + k * 32 + h];
    w1T[(size_t)j * 128 + k] = f2b(s);
}

// w2T[j2][h] = sum_b comps2[r,b]*bases2[b,h,c], j2=r*16+c  (bf16, [512][32])
__global__ __launch_bounds__(256) void kw2(const float* __restrict__ comps2,
                                           const float* __restrict__ bases2,
                                           unsigned short* __restrict__ w2T) {
    int id = blockIdx.x * 256 + threadIdx.x;
    if (id >= 512 * 32) return;
    int h = id & 31, j = id >> 5;
    int r = j >> 4, c = j & 15;
    float s = 0.f;
#pragma unroll
    for (int b = 0; b < 16; b++)
        s += comps2[r * 16 + b] * bases2[b * 512 + h * 16 + c];
    w2T[(size_t)j * 32 + h] = f2b(s);
}

// Single-pass in-block counting sort by bucket (fr>>8).
// word=(frlo<<22)|(rel<<17)|to.  Per-bucket runs flushed contiguously.
__global__ __launch_bounds__(256) void kbinA(const int* __restrict__ rel,
                                             const int* __restrict__ fr,
                                             const int* __restrict__ to,
                                             int* __restrict__ gCursor,
                                             unsigned int* __restrict__ stage) {
    __shared__ int cnt[NB];
    __shared__ int lexcl[NB + 1];
    __shared__ int sdelta[NB];
    __shared__ int sa[512], sb_[512];
    __shared__ unsigned int sortbuf[EPB];
    int tid = threadIdx.x;
    int g40 = blockIdx.x * (EPB / 4);          // int4-group base
    unsigned int w_[32];
    int bk[32];
    for (int i = tid; i < NB; i += 256) cnt[i] = 0;
    __syncthreads();
    // load 32 edges into registers, LDS histogram
#pragma unroll
    for (int i = 0; i < 8; i++) {
        int g4 = g40 + i * 256 + tid;
        if (g4 < E_EDGES / 4) {
            int4 f4 = ((const int4*)fr)[g4];
            int4 r4 = ((const int4*)rel)[g4];
            int4 t4 = ((const int4*)to)[g4];
            int fa[4] = {f4.x, f4.y, f4.z, f4.w};
            int ra[4] = {r4.x, r4.y, r4.z, r4.w};
            int ta[4] = {t4.x, t4.y, t4.z, t4.w};
#pragma unroll
            for (int u = 0; u < 4; u++) {
                int b = fa[u] >> 8;
                w_[i * 4 + u] = ((unsigned int)(fa[u] & 255) << 22) |
                                ((unsigned int)ra[u] << 17) | (unsigned int)ta[u];
                bk[i * 4 + u] = b;
                atomicAdd(&cnt[b], 1);
            }
        } else {
#pragma unroll
            for (int u = 0; u < 4; u++) bk[i * 4 + u] = -1;
        }
    }
    __syncthreads();
    // inclusive scan of cnt[0..NB) over padded 512 domain (256 thr x 2 elem)
    sa[tid] = (tid < NB) ? cnt[tid] : 0;
    sa[tid + 256] = (tid + 256 < NB) ? cnt[tid + 256] : 0;
    __syncthreads();
    int* src = sa; int* dst = sb_;
    for (int ofs = 1; ofs < 512; ofs <<= 1) {
        int x0 = src[tid];
        if (tid >= ofs) x0 += src[tid - ofs];
        int x1 = src[tid + 256] + src[tid + 256 - ofs];
        __syncthreads();
        dst[tid] = x0; dst[tid + 256] = x1;
        __syncthreads();
        int* tmp = src; src = dst; dst = tmp;
    }
    // reserve global ranges, build local offsets
    for (int b = tid; b < NB; b += 256) {
        int c = cnt[b];
        int lex = src[b] - c;
        lexcl[b] = lex;
        int gb = 0;
        if (c) gb = atomicAdd(&gCursor[b], c);
        sdelta[b] = gb - lex;
        cnt[b] = 0;                       // reuse as rank counter
    }
    if (tid == 0) lexcl[NB] = src[NB - 1];
    __syncthreads();
    // rank-scatter into LDS sorted buffer
#pragma unroll
    for (int i = 0; i < 32; i++) {
        if (bk[i] >= 0) {
            int rank = atomicAdd(&cnt[bk[i]], 1);
            sortbuf[lexcl[bk[i]] + rank] = w_[i];
        }
    }
    __syncthreads();
    // flush per-bucket contiguous runs
    int wv = tid >> 6, lane = tid & 63;
    for (int b = wv; b < NB; b += 4) {
        int s = lexcl[b], e = lexcl[b + 1];
        int d = sdelta[b];
        for (int i = s + lane; i < e; i += 64)
            stage[d + i] = sortbuf[i];
    }
}

// exclusive scan of bucket counts -> bucketBase
__global__ __launch_bounds__(512) void kscan(const int* __restrict__ gCursor,
                                             int* __restrict__ bucketBase) {
    __shared__ int a[512], b[512];
    int t = threadIdx.x;
    int v = (t < NB) ? (gCursor[t] - t * BCAP) : 0;
    a[t] = v;
    __syncthreads();
    int* src = a; int* dst = b;
    for (int ofs = 1; ofs < 512; ofs <<= 1) {
        int x = src[t];
        if (t >= ofs) x += src[t - ofs];
        __syncthreads();
        dst[t] = x;
        __syncthreads();
        int* tmp = src; src = dst; dst = tmp;
    }
    if (t < NB) bucketBase[t] = src[t] - v;
}

// Per-bucket: LDS node-hist -> scan -> rowptr; (node,rel)-hist -> deg;
// scatter packed = (deg<<22)|(rel<<17)|to.  uint4 stage loads.
__global__ __launch_bounds__(256) void kscatter2(const unsigned int* __restrict__ stage,
                                                 const int* __restrict__ gCursor,
                                                 const int* __restrict__ bucketBase,
                                                 int* __restrict__ rowptr,
                                                 unsigned int* __restrict__ packed) {
    __shared__ int hist[256], hexcl[256], rk[256], sa[256], sb[256];
    __shared__ int hist2[256 * 32];
    int b = blockIdx.x, t = threadIdx.x;
    int nb = gCursor[b] - b * BCAP;
    int sbase = b * BCAP;
    int gbase = bucketBase[b];
    int nb4 = nb >> 2;
    hist[t] = 0; rk[t] = 0;
    for (int i = t; i < 256 * 32; i += 256) hist2[i] = 0;
    __syncthreads();
    for (int i4 = t; i4 < nb4; i4 += 256) {
        uint4 p4 = ((const uint4*)(stage + sbase))[i4];
        unsigned int pa[4] = {p4.x, p4.y, p4.z, p4.w};
#pragma unroll
        for (int u = 0; u < 4; u++) {
            atomicAdd(&hist[pa[u] >> 22], 1);
            atomicAdd(&hist2[((pa[u] >> 22) << 5) | ((pa[u] >> 17) & 31)], 1);
        }
    }
    for (int i = (nb4 << 2) + t; i < nb; i += 256) {
        unsigned int pk = stage[sbase + i];
        atomicAdd(&hist[pk >> 22], 1);
        atomicAdd(&hist2[((pk >> 22) << 5) | ((pk >> 17) & 31)], 1);
    }
    __syncthreads();
    int v = hist[t];
    sa[t] = v;
    __syncthreads();
    int* src = sa; int* dst = sb;
    for (int ofs = 1; ofs < 256; ofs <<= 1) {
        int x = src[t];
        if (t >= ofs) x += src[t - ofs];
        __syncthreads();
        dst[t] = x;
        __syncthreads();
        int* tmp = src; src = dst; dst = tmp;
    }
    int excl = src[t] - v;
    hexcl[t] = excl;
    rowptr[b * 256 + t] = gbase + excl;
    __syncthreads();
    for (int i4 = t; i4 < nb4; i4 += 256) {
        uint4 p4 = ((const uint4*)(stage + sbase))[i4];
        unsigned int pa[4] = {p4.x, p4.y, p4.z, p4.w};
#pragma unroll
        for (int u = 0; u < 4; u++) {
            int frlo = pa[u] >> 22;
            int rank = atomicAdd(&rk[frlo], 1);
            int dg = min(hist2[(frlo << 5) | ((pa[u] >> 17) & 31)], 1023);
            packed[gbase + hexcl[frlo] + rank] = ((unsigned int)dg << 22) | (pa[u] & 0x3FFFFFu);
        }
    }
    for (int i = (nb4 << 2) + t; i < nb; i += 256) {
        unsigned int pk = stage[sbase + i];
        int frlo = pk >> 22;
        int rank = atomicAdd(&rk[frlo], 1);
        int dg = min(hist2[(frlo << 5) | ((pk >> 17) & 31)], 1023);
        packed[gbase + hexcl[frlo] + rank] = ((unsigned int)dg << 22) | (pk & 0x3FFFFFu);
    }
}

// GEMM1 (row-shared block + merged wide epilogue): xw[m][j] = sum_k embb[m][k]*w1T[j][k].
// Block: 4 waves share the SAME 16 rows, each wave owns 64 cols (bn=bn4*4+w).
// Per iter: 16 MFMA/wave -> cvt_pk into shared LDS tile [16][256] (stride 260)
// -> barrier -> block stores 512B-contiguous per row (2 uint4/thread) -> barrier.
// Consecutive blocks (bn4 0..3 of same mg) write complementary cols of the
// same rows -> DRAM-page-local write streams.
__global__ __launch_bounds__(256) void gemm1(const unsigned short* __restrict__ embb,
                                             const unsigned short* __restrict__ w1T,
                                             unsigned short* __restrict__ xw) {
    __shared__ unsigned short tile[16 * 260];
    int id = blockIdx.x;
    int bn4 = id & 3, mg = id >> 2;            // mg in [0, 392)
    int mrow0 = mg * 256;
    if (mrow0 >= N_PAD) return;                // mg=391 is empty (392*256 > N_PAD)
    int lane = threadIdx.x & 63, wave = threadIdx.x >> 6;
    int bn = bn4 * 4 + wave;
    int m_ = lane & 15, q = lane >> 4;
    bf16x8 B[4][4];
    const unsigned short* Bbase = w1T + (size_t)(bn * 64 + m_) * 128 + q * 8;
#pragma unroll
    for (int j = 0; j < 4; j++)
#pragma unroll
        for (int k0 = 0; k0 < 4; k0++)
            B[j][k0] = *(const bf16x8*)(Bbase + j * 16 * 128 + k0 * 32);
    const unsigned short* Abase = embb + (size_t)(mrow0 + m_) * 128 + q * 8;
    bf16x8 a0[4], a1[4];
#pragma unroll
    for (int k0 = 0; k0 < 4; k0++)
        a0[k0] = *(const bf16x8*)(Abase + k0 * 32);
#pragma unroll
    for (int t = 0; t < 16; t++) {
        int m0 = mrow0 + t * 16;
        bf16x8* acur = (t & 1) ? a1 : a0;
        bf16x8* anext = (t & 1) ? a0 : a1;
        if (t < 15) {
#pragma unroll
            for (int k0 = 0; k0 < 4; k0++)
                anext[k0] = *(const bf16x8*)(Abase + (size_t)(t + 1) * 16 * 128 + k0 * 32);
        }
        f32x4 acc[4] = {};
#pragma unroll
        for (int k0 = 0; k0 < 4; k0++)
#pragma unroll
            for (int j = 0; j < 4; j++)
                acc[j] = __builtin_amdgcn_mfma_f32_16x16x32_bf16(B[j][k0], acur[k0], acc[j], 0, 0, 0);
        // pack: row m_, cols wave*64 + jj*16 + q*4 (+reg)
#pragma unroll
        for (int jj = 0; jj < 4; jj++) {
            uint2 s;
            s.x = cvt2(acc[jj][0], acc[jj][1]);
            s.y = cvt2(acc[jj][2], acc[jj][3]);
            *(uint2*)(tile + m_ * 260 + wave * 64 + jj * 16 + q * 4) = s;
        }
        __syncthreads();
        // merged store: 512 uint4 chunks (16 rows x 512B), 2 per thread
#pragma unroll
        for (int half = 0; half < 2; half++) {
            int idx = threadIdx.x + half * 256;
            int row = idx >> 5, c16 = idx & 31;
            uint4 v = *(const uint4*)(tile + row * 260 + c16 * 8);
            int grow = m0 + row;
            if (grow < N_NODES)
                *(uint4*)(xw + (size_t)grow * 1024 + bn4 * 256 + c16 * 8) = v;
        }
        __syncthreads();
    }
}

// edge1csr: one wave per node, single pass (deg packed).  8 edges/instr.
__global__ __launch_bounds__(256) void edge1csr(const unsigned int* __restrict__ packed,
                                                const int* __restrict__ rowptr,
                                                const unsigned short* __restrict__ xw,
                                                const float* __restrict__ bias1,
                                                unsigned short* __restrict__ h1b) {
    __shared__ unsigned int ebuf[4 * 64];
    __shared__ float vbuf[4 * 64];
    int wave = threadIdx.x >> 6, lane = threadIdx.x & 63;
    int f = blockIdx.x * 4 + wave;
    if (f >= N_NODES) return;
    int s = rowptr[f], k = rowptr[f + 1] - s;
    int sub = lane & 7, p = lane >> 3;
    f32x4 acc = {0.f, 0.f, 0.f, 0.f};
    for (int base = 0; base < k; base += 64) {
        int e = base + lane;
        if (e < k) {
            unsigned int pk = packed[s + e];
            ebuf[wave * 64 + lane] = pk;
            vbuf[wave * 64 + lane] = 1.0f / (float)(pk >> 22);
        }
        int cnum = min(64, k - base);
        int nst = (cnum + 7) >> 3;
#pragma unroll 4
        for (int i = 0; i < nst; i++) {
            int ei = (i << 3) + p;
            if (ei < cnum) {
                unsigned int pk = ebuf[wave * 64 + ei];
                float v = vbuf[wave * 64 + ei];
                int t_ = pk & 0x1FFFF, r = (pk >> 17) & 31;
                ushort4 raw = *(const ushort4*)(xw + (size_t)t_ * 1024 + (r << 5) + (sub << 2));
                acc.x += v * b2f(raw.x); acc.y += v * b2f(raw.y);
                acc.z += v * b2f(raw.z); acc.w += v * b2f(raw.w);
            }
        }
    }
#pragma unroll
    for (int ofs = 8; ofs < 64; ofs <<= 1) {
        acc.x += __shfl_xor(acc.x, ofs, 64);
        acc.y += __shfl_xor(acc.y, ofs, 64);
        acc.z += __shfl_xor(acc.z, ofs, 64);
        acc.w += __shfl_xor(acc.w, ofs, 64);
    }
    if (p == 0) {
        int h = sub << 2;
        ushort4 o;
        o.x = f2b(fmaxf(acc.x + bias1[h + 0], 0.f));
        o.y = f2b(fmaxf(acc.y + bias1[h + 1], 0.f));
        o.z = f2b(fmaxf(acc.z + bias1[h + 2], 0.f));
        o.w = f2b(fmaxf(acc.w + bias1[h + 3], 0.f));
        *(ushort4*)(h1b + (size_t)f * 32 + h) = o;
    }
}

// GEMM2 (streaming-wave + LDS-pack epilogue, R11): z[m][j2] = sum_h h1b[m][h]*w2T[j2][h].
__global__ __launch_bounds__(256) void gemm2(const unsigned short* __restrict__ h1b,
                                             const unsigned short* __restrict__ w2T,
                                             unsigned short* __restrict__ z) {
    __shared__ unsigned short ldsT[4 * 16 * 136];
    int id = blockIdx.x;
    int xcd = id & 7, w = id >> 3;
    int bn = w & 7, mgl = w >> 3;
    int mg = mgl * 8 + xcd;
    if (mg >= 98) return;
    int lane = threadIdx.x & 63, wave = threadIdx.x >> 6;
    int m_ = lane & 15, q = lane >> 4;
    unsigned short* tw = &ldsT[wave * 16 * 136];
    bf16x8 B[4];
    const unsigned short* Bbase = w2T + (size_t)(bn * 64 + m_) * 32 + q * 8;
#pragma unroll
    for (int j = 0; j < 4; j++)
        B[j] = *(const bf16x8*)(Bbase + j * 16 * 32);
    int mrow0 = mg * 1024 + wave * 32;
    const unsigned short* Abase = h1b + (size_t)(mrow0 + m_) * 32 + q * 8;
    bf16x8 a0[2], a1[2];
    if (mrow0 < N_PAD) {
        a0[0] = *(const bf16x8*)(Abase);
        a0[1] = *(const bf16x8*)(Abase + 16 * 32);
    }
#pragma unroll
    for (int t = 0; t < 8; t++) {
        int m0 = mrow0 + t * 128;
        if (m0 >= N_PAD) break;
        bf16x8* acur = (t & 1) ? a1 : a0;
        bf16x8* anext = (t & 1) ? a0 : a1;
        if (t < 7 && m0 + 128 < N_PAD) {
            anext[0] = *(const bf16x8*)(Abase + (size_t)(t + 1) * 128 * 32);
            anext[1] = *(const bf16x8*)(Abase + (size_t)(t + 1) * 128 * 32 + 16 * 32);
        }
        f32x4 acc[2][4] = {};
#pragma unroll
        for (int i = 0; i < 2; i++)
#pragma unroll
            for (int j = 0; j < 4; j++)
                acc[i][j] = __builtin_amdgcn_mfma_f32_16x16x32_bf16(B[j], acur[i], acc[i][j], 0, 0, 0);
#pragma unroll
        for (int i = 0; i < 2; i++) {
#pragma unroll
            for (int jj = 0; jj < 4; jj++) {
                ushort4 s;
                s.x = f2b(acc[i][jj][0]); s.y = f2b(acc[i][jj][1]);
                s.z = f2b(acc[i][jj][2]); s.w = f2b(acc[i][jj][3]);
                *(ushort4*)(tw + m_ * 136 + jj * 16 + q * 4) = s;
            }
            __asm__ volatile("s_waitcnt lgkmcnt(0)" ::: "memory");
#pragma unroll
            for (int ri = 0; ri < 2; ri++) {
                int row = (lane >> 3) + ri * 8;
                int c = lane & 7;
                uint4 v = *(const uint4*)(tw + row * 136 + c * 8);
                int grow = m0 + i * 16 + row;
                if (grow < N_NODES)
                    *(uint4*)(z + (size_t)grow * 512 + bn * 64 + c * 8) = v;
            }
            __asm__ volatile("s_waitcnt lgkmcnt(0)" ::: "memory");
        }
    }
}

// edge2csr: one wave per node, single pass.  16 edges/instr, float4 store.
__global__ __launch_bounds__(256) void edge2csr(const unsigned int* __restrict__ packed,
                                                const int* __restrict__ rowptr,
                                                const unsigned short* __restrict__ z,
                                                const float* __restrict__ bias2,
                                                float* __restrict__ out) {
    __shared__ unsigned int ebuf[4 * 64];
    __shared__ float vbuf[4 * 64];
    int wave = threadIdx.x >> 6, lane = threadIdx.x & 63;
    int f = blockIdx.x * 4 + wave;
    if (f >= N_NODES) return;
    int s = rowptr[f], k = rowptr[f + 1] - s;
    int sub = lane & 3, p = lane >> 2;
    f32x4 acc = {0.f, 0.f, 0.f, 0.f};
    for (int base = 0; base < k; base += 64) {
        int e = base + lane;
        if (e < k) {
            unsigned int pk = packed[s + e];
            ebuf[wave * 64 + lane] = pk;
            vbuf[wave * 64 + lane] = 1.0f / (float)(pk >> 22);
        }
        int cnum = min(64, k - base);
        int nst = (cnum + 15) >> 4;
#pragma unroll 4
        for (int i = 0; i < nst; i++) {
            int ei = (i << 4) + p;
            if (ei < cnum) {
                unsigned int pk = ebuf[wave * 64 + ei];
                float v = vbuf[wave * 64 + ei];
                int t_ = pk & 0x1FFFF, r = (pk >> 17) & 31;
                ushort4 raw = *(const ushort4*)(z + (size_t)t_ * 512 + (r << 4) + (sub << 2));
                acc.x += v * b2f(raw.x); acc.y += v * b2f(raw.y);
                acc.z += v * b2f(raw.z); acc.w += v * b2f(raw.w);
            }
        }
    }
#pragma unroll
    for (int ofs = 4; ofs < 64; ofs <<= 1) {
        acc.x += __shfl_xor(acc.x, ofs, 64);
        acc.y += __shfl_xor(acc.y, ofs, 64);
        acc.z += __shfl_xor(acc.z, ofs, 64);
        acc.w += __shfl_xor(acc.w, ofs, 64);
    }
    if (p == 0) {
        int c = sub << 2;
        float4 o;
        o.x = acc.x + bias2[c + 0];
        o.y = acc.y + bias2[c + 1];
        o.z = acc.z + bias2[c + 2];
        o.w = acc.w + bias2[c + 3];
        *(float4*)(out + (size_t)f * 16 + c) = o;
    }
}

extern "C" void kernel_launch(void* const* d_in, const int* in_sizes, int n_in,
                              void* d_out, int out_size, void* d_ws, size_t ws_size,
                              hipStream_t stream) {
    (void)in_sizes; (void)n_in; (void)out_size; (void)ws_size;
    const float* emb    = (const float*)d_in[0];
    const float* comps1 = (const float*)d_in[1];
    const float* bases1 = (const float*)d_in[2];
    const float* comps2 = (const float*)d_in[3];
    const float* bases2 = (const float*)d_in[4];
    const float* bias1  = (const float*)d_in[5];
    const float* bias2  = (const float*)d_in[6];
    const int* rel = (const int*)d_in[7];
    const int* fr  = (const int*)d_in[8];
    const int* to  = (const int*)d_in[9];
    float* out = (float*)d_out;
    char* ws = (char*)d_ws;

    // workspace layout (bytes); total ~250.3 MB
    int* gCursor         = (int*)(ws);                        // 1,568
    int* bucketBase      = (int*)(ws + 2048);                 // 1,568
    int* rowptr          = (int*)(ws + 4096);                 // 401,412
    unsigned int* packed = (unsigned int*)(ws + 406528);      // 12,800,000
    unsigned short* h1b  = (unsigned short*)(ws + 13206528);  // 6,406,144 (N_PAD x 32)
    unsigned short* w1T  = (unsigned short*)(ws + 19612672);  // 262,144
    unsigned short* w2T  = (unsigned short*)(ws + 19874816);  // 32,768
    unsigned short* embb = (unsigned short*)(ws + 19907584);  // 25,624,576 (N_PAD x 128)
    unsigned short* xw   = (unsigned short*)(ws + 45532160);  // 204,800,000
    unsigned short* z    = xw;                 // alias: xw dead before gemm2
    unsigned int* stage  = (unsigned int*)xw;  // alias: stage dead before gemm1

    kcur<<<2, 256, 0, stream>>>(gCursor);
    kemb<<<6256, 256, 0, stream>>>(emb, embb);
    kw1<<<512, 256, 0, stream>>>(comps1, bases1, w1T);
    kw2<<<64, 256, 0, stream>>>(comps2, bases2, w2T);
    kbinA<<<(E_EDGES + EPB - 1) / EPB, 256, 0, stream>>>(rel, fr, to, gCursor, stage);
    kscan<<<1, 512, 0, stream>>>(gCursor, bucketBase);
    kscatter2<<<NB, 256, 0, stream>>>(stage, gCursor, bucketBase, rowptr, packed);
    gemm1<<<1568, 256, 0, stream>>>(embb, w1T, xw);    // 4 bn4 * 392 mg
    edge1csr<<<25000, 256, 0, stream>>>(packed, rowptr, xw, bias1, h1b);
    gemm2<<<832, 256, 0, stream>>>(h1b, w2T, z);       // 8 xcd * 8 bn * 13 mgl
    edge2csr<<<25000, 256, 0, stream>>>(packed, rowptr, z, bias2, out);
}